// Round 2
// baseline (961.255 us; speedup 1.0000x reference)
//
#include <hip/hip_runtime.h>
#include <hip/hip_bf16.h>

// MoE FFN (dMoE), MI355X. Round 2: bf16 MFMA GEMMs (m97-style structure).
// Shapes: T=4096 tokens, D=1024, F=4096, E=8, K=2, C=1280.
//
// Pipeline:
//   k_cvt        : w12,w3 fp32 -> bf16 (per call; ws is re-poisoned)
//   k_ln_router  : LayerNorm + router logits + top-2 (fp32), writes xn as bf16
//   k_dispatch   : stable per-expert prefix scan -> slot_row / row_tok / counts
//   k_gemm1      : gathered-A bf16 MFMA, two K-passes (g then u), fused SwiGLU
//   k_gemm2      : bf16 MFMA, fp32 out
//   k_combine    : weighted gather-combine
//
// ws layout (bytes), total ~320.2 MiB:
//   xnb   bf16 [T,D]        @ 0
//   w12b  bf16 [E,2F,D]     @ 8388608
//   w3b   bf16 [E,D,F]      @ 142606336
//   h     bf16 [E*C,F]      @ 209715200
//   yb    f32  [E*C,D]      @ 293601280
//   slot_e   int [T*K]      @ 335544320
//   slot_w   f32 [T*K]      @ 335577088
//   slot_row int [T*K]      @ 335609856
//   row_tok  int [E*C]      @ 335642624
//   counts   int [E]        @ 335683584

#define T_TOK   4096
#define DM      1024
#define DFF     4096
#define NE      8
#define C_CAP   1280
#define CLAMP_V 1.0e4f
#define LN_EPS  1e-5f

typedef __attribute__((ext_vector_type(8))) __bf16 bf16x8;
typedef __attribute__((ext_vector_type(4))) __bf16 bf16x4;
typedef __attribute__((ext_vector_type(4))) float  f32x4;

#define GLOAD16(gsrc, ldst)                                                      \
    __builtin_amdgcn_global_load_lds(                                            \
        (const __attribute__((address_space(1))) void*)(gsrc),                   \
        (__attribute__((address_space(3))) void*)(ldst), 16, 0, 0)

// ---------------- kernel 0: fp32 -> bf16 weight conversion ----------------
__global__ __launch_bounds__(256) void k_cvt(const float* __restrict__ s,
                                             __bf16* __restrict__ d, int n4)
{
    int i = blockIdx.x * 256 + threadIdx.x;
    const int stride = gridDim.x * 256;
    for (; i < n4; i += stride) {
        const float4 v = ((const float4*)s)[i];
        bf16x4 o;
        o.x = (__bf16)v.x; o.y = (__bf16)v.y; o.z = (__bf16)v.z; o.w = (__bf16)v.w;
        ((bf16x4*)d)[i] = o;
    }
}

// ---------------- kernel 1: LayerNorm + router logits + top-2 ----------------
__global__ __launch_bounds__(256) void k_ln_router(
    const float* __restrict__ x, const float* __restrict__ gamma,
    const float* __restrict__ beta, const float* __restrict__ rw,
    __bf16* __restrict__ xnb, int* __restrict__ slot_e, float* __restrict__ slot_w)
{
    const int t   = blockIdx.x;
    const int tid = threadIdx.x;
    __shared__ float lds4[4];
    __shared__ float red[4][8];
    __shared__ float logits[8];

    const float4 xv = *(const float4*)(x + (size_t)t * DM + tid * 4);

    float s = xv.x + xv.y + xv.z + xv.w;
    #pragma unroll
    for (int o = 32; o > 0; o >>= 1) s += __shfl_down(s, o, 64);
    if ((tid & 63) == 0) lds4[tid >> 6] = s;
    __syncthreads();
    const float mu = (lds4[0] + lds4[1] + lds4[2] + lds4[3]) * (1.0f / DM);

    float4 d4;
    d4.x = xv.x - mu; d4.y = xv.y - mu; d4.z = xv.z - mu; d4.w = xv.w - mu;
    float v = d4.x*d4.x + d4.y*d4.y + d4.z*d4.z + d4.w*d4.w;
    #pragma unroll
    for (int o = 32; o > 0; o >>= 1) v += __shfl_down(v, o, 64);
    __syncthreads();
    if ((tid & 63) == 0) lds4[tid >> 6] = v;
    __syncthreads();
    const float rstd = rsqrtf((lds4[0]+lds4[1]+lds4[2]+lds4[3]) * (1.0f/DM) + LN_EPS);

    const float4 g4 = *(const float4*)(gamma + tid * 4);
    const float4 b4 = *(const float4*)(beta + tid * 4);
    float4 xnv;
    xnv.x = d4.x * rstd * g4.x + b4.x;
    xnv.y = d4.y * rstd * g4.y + b4.y;
    xnv.z = d4.z * rstd * g4.z + b4.z;
    xnv.w = d4.w * rstd * g4.w + b4.w;
    bf16x4 xb;
    xb.x = (__bf16)xnv.x; xb.y = (__bf16)xnv.y; xb.z = (__bf16)xnv.z; xb.w = (__bf16)xnv.w;
    *(bf16x4*)(xnb + (size_t)t * DM + tid * 4) = xb;

    float part[8];
    #pragma unroll
    for (int e = 0; e < 8; ++e) {
        const float4 w4 = *(const float4*)(rw + (size_t)e * DM + tid * 4);
        part[e] = xnv.x*w4.x + xnv.y*w4.y + xnv.z*w4.z + xnv.w*w4.w;
    }
    #pragma unroll
    for (int e = 0; e < 8; ++e) {
        float p = part[e];
        #pragma unroll
        for (int o = 32; o > 0; o >>= 1) p += __shfl_down(p, o, 64);
        if ((tid & 63) == 0) red[tid >> 6][e] = p;
    }
    __syncthreads();
    if (tid < 8) {
        float l = red[0][tid] + red[1][tid] + red[2][tid] + red[3][tid];
        l = fminf(fmaxf(l, -CLAMP_V), CLAMP_V);
        logits[tid] = l;
    }
    __syncthreads();
    if (tid == 0) {
        int i0 = 0; float v0 = logits[0];
        #pragma unroll
        for (int e = 1; e < 8; ++e) { if (logits[e] > v0) { v0 = logits[e]; i0 = e; } }
        int i1 = (i0 == 0) ? 1 : 0; float v1 = logits[i1];
        #pragma unroll
        for (int e = 0; e < 8; ++e) {
            if (e == i0 || e == ((i0 == 0) ? 1 : 0)) continue;
            if (logits[e] > v1) { v1 = logits[e]; i1 = e; }
        }
        const float ex = __expf(v1 - v0);
        const float denom = 1.0f + ex + 1e-12f;
        slot_e[2*t]   = i0;
        slot_e[2*t+1] = i1;
        slot_w[2*t]   = 1.0f / denom;
        slot_w[2*t+1] = ex / denom;
    }
}

// ---------------- kernel 2: stable dispatch scan (single block) ----------------
__global__ __launch_bounds__(256) void k_dispatch(
    const int* __restrict__ slot_e, int* __restrict__ slot_row,
    int* __restrict__ row_tok, int* __restrict__ counts)
{
    __shared__ int cnt[256][NE];
    const int tid = threadIdx.x;

    for (int i = tid; i < NE * C_CAP; i += 256) row_tok[i] = -1;

    int loc[NE];
    #pragma unroll
    for (int e = 0; e < NE; ++e) loc[e] = 0;
    const int s0 = tid * 32;
    for (int s = s0; s < s0 + 32; ++s) {
        const int e = slot_e[s];
        #pragma unroll
        for (int ee = 0; ee < NE; ++ee) loc[ee] += (e == ee);   // static idx (rule #20)
    }
    #pragma unroll
    for (int e = 0; e < NE; ++e) cnt[tid][e] = loc[e];
    __syncthreads();

    if (tid < NE) {
        int run = 0;
        for (int t2 = 0; t2 < 256; ++t2) { const int v2 = cnt[t2][tid]; cnt[t2][tid] = run; run += v2; }
        counts[tid] = run < C_CAP ? run : C_CAP;
    }
    __syncthreads();

    #pragma unroll
    for (int e = 0; e < NE; ++e) loc[e] = cnt[tid][e];
    for (int s = s0; s < s0 + 32; ++s) {
        const int e = slot_e[s];
        int pos = 0;
        #pragma unroll
        for (int ee = 0; ee < NE; ++ee) if (e == ee) { pos = loc[ee]; loc[ee] = pos + 1; }
        if (pos < C_CAP) {
            const int row = e * C_CAP + pos;
            slot_row[s] = row;
            row_tok[row] = s >> 1;
        } else {
            slot_row[s] = -1;
        }
    }
}

// ---------------- kernel 3: GEMM1 bf16 MFMA + fused SwiGLU (two K-passes) -----
// 128x128 tile, 4 waves (2x2), each wave 64x64 via 4x4 frags of 16x16x32.
// pass0: g = xn . w12[e][nt*128.. ][:]   (stash bf16 in LDS Gs)
// pass1: u = xn . w12[e][4096+nt*128..][:]; h = silu(g)*u (bf16)
__global__ __launch_bounds__(256) void k_gemm1(
    const __bf16* __restrict__ xnb, const __bf16* __restrict__ w12b,
    const int* __restrict__ row_tok, const int* __restrict__ counts,
    __bf16* __restrict__ h)
{
    const int e  = blockIdx.z;
    const int nt = blockIdx.y;   // 0..31 (g-column tile)
    const int mt = blockIdx.x;   // 0..9
    if (mt * 128 >= counts[e]) return;

    __shared__ __align__(16) __bf16 As[128 * 32];   // 8 KB
    __shared__ __align__(16) __bf16 Bs[128 * 32];   // 8 KB
    __shared__ __align__(16) __bf16 Gs[128 * 128];  // 32 KB g stash

    const int tid  = threadIdx.x;
    const int wid  = tid >> 6, lane = tid & 63;
    const int wr   = wid >> 1, wc = wid & 1;

    // staging maps: idx = i*256 + tid ; row = idx>>2 ; 16B chunk = idx&3
    const int r0 = tid >> 2,        kc0 = (tid & 3) * 8;
    const int r1 = (256 + tid) >> 2, kc1 = ((256 + tid) & 3) * 8;
    int t0 = row_tok[e * C_CAP + mt * 128 + r0]; if (t0 < 0) t0 = 0;
    int t1 = row_tok[e * C_CAP + mt * 128 + r1]; if (t1 < 0) t1 = 0;
    const __bf16* a0 = xnb + (size_t)t0 * DM + kc0;
    const __bf16* a1 = xnb + (size_t)t1 * DM + kc1;
    const int ld0 = (wid * 64) * 8;          // bf16 elements (wave-uniform)
    const int ld1 = (256 + wid * 64) * 8;

    const int lr = lane & 15, lk = (lane >> 4) * 8;
    const int a_base = (wr * 64 + lr) * 32 + lk;
    const int b_base = (wc * 64 + lr) * 32 + lk;
    const int rbase  = (lane >> 4) * 4;

    f32x4 acc[4][4];
    #pragma unroll
    for (int mi = 0; mi < 4; ++mi)
        #pragma unroll
        for (int ni = 0; ni < 4; ++ni) acc[mi][ni] = (f32x4){0.f, 0.f, 0.f, 0.f};

    #pragma unroll
    for (int pass = 0; pass < 2; ++pass) {
        const __bf16* b0 = w12b + ((size_t)e * (2*DFF) + pass * DFF + nt * 128 + r0) * DM + kc0;
        const __bf16* b1 = w12b + ((size_t)e * (2*DFF) + pass * DFF + nt * 128 + r1) * DM + kc1;

        for (int k0 = 0; k0 < DM; k0 += 32) {
            __syncthreads();
            GLOAD16(a0 + k0, As + ld0);
            GLOAD16(a1 + k0, As + ld1);
            GLOAD16(b0 + k0, Bs + ld0);
            GLOAD16(b1 + k0, Bs + ld1);
            asm volatile("s_waitcnt vmcnt(0)" ::: "memory");
            __syncthreads();

            bf16x8 a[4];
            #pragma unroll
            for (int mi = 0; mi < 4; ++mi)
                a[mi] = *(const bf16x8*)&As[a_base + mi * 512];
            #pragma unroll
            for (int ni = 0; ni < 4; ++ni) {
                const bf16x8 b = *(const bf16x8*)&Bs[b_base + ni * 512];
                #pragma unroll
                for (int mi = 0; mi < 4; ++mi)
                    acc[mi][ni] = __builtin_amdgcn_mfma_f32_16x16x32_bf16(a[mi], b, acc[mi][ni], 0, 0, 0);
            }
        }

        if (pass == 0) {
            // stash g (same lane re-reads it in pass1 epilogue -> no barrier needed)
            #pragma unroll
            for (int mi = 0; mi < 4; ++mi)
                #pragma unroll
                for (int ni = 0; ni < 4; ++ni) {
                    #pragma unroll
                    for (int r = 0; r < 4; ++r) {
                        const int row = wr * 64 + mi * 16 + rbase + r;
                        const int col = wc * 64 + ni * 16 + lr;
                        Gs[row * 128 + col] = (__bf16)acc[mi][ni][r];
                    }
                    acc[mi][ni] = (f32x4){0.f, 0.f, 0.f, 0.f};
                }
        } else {
            #pragma unroll
            for (int mi = 0; mi < 4; ++mi)
                #pragma unroll
                for (int ni = 0; ni < 4; ++ni)
                    #pragma unroll
                    for (int r = 0; r < 4; ++r) {
                        const int row = wr * 64 + mi * 16 + rbase + r;
                        const int col = wc * 64 + ni * 16 + lr;
                        const float g = (float)Gs[row * 128 + col];
                        const float u = acc[mi][ni][r];
                        const float o = (g / (1.0f + __expf(-g))) * u;
                        h[(size_t)(e * C_CAP + mt * 128 + row) * DFF + nt * 128 + col] = (__bf16)o;
                    }
        }
    }
}

// ---------------- kernel 4: GEMM2 bf16 MFMA, fp32 out ----------------
__global__ __launch_bounds__(256) void k_gemm2(
    const __bf16* __restrict__ h, const __bf16* __restrict__ w3b,
    const int* __restrict__ counts, float* __restrict__ yb)
{
    const int e  = blockIdx.z;
    const int nt = blockIdx.y;   // 0..7
    const int mt = blockIdx.x;   // 0..9
    if (mt * 128 >= counts[e]) return;

    __shared__ __align__(16) __bf16 As[128 * 32];
    __shared__ __align__(16) __bf16 Bs[128 * 32];

    const int tid  = threadIdx.x;
    const int wid  = tid >> 6, lane = tid & 63;
    const int wr   = wid >> 1, wc = wid & 1;

    const int r0 = tid >> 2,         kc0 = (tid & 3) * 8;
    const int r1 = (256 + tid) >> 2, kc1 = ((256 + tid) & 3) * 8;
    const __bf16* a0 = h + (size_t)(e * C_CAP + mt * 128 + r0) * DFF + kc0;
    const __bf16* a1 = h + (size_t)(e * C_CAP + mt * 128 + r1) * DFF + kc1;
    const __bf16* b0 = w3b + ((size_t)e * DM + nt * 128 + r0) * DFF + kc0;
    const __bf16* b1 = w3b + ((size_t)e * DM + nt * 128 + r1) * DFF + kc1;
    const int ld0 = (wid * 64) * 8;
    const int ld1 = (256 + wid * 64) * 8;

    const int lr = lane & 15, lk = (lane >> 4) * 8;
    const int a_base = (wr * 64 + lr) * 32 + lk;
    const int b_base = (wc * 64 + lr) * 32 + lk;
    const int rbase  = (lane >> 4) * 4;

    f32x4 acc[4][4];
    #pragma unroll
    for (int mi = 0; mi < 4; ++mi)
        #pragma unroll
        for (int ni = 0; ni < 4; ++ni) acc[mi][ni] = (f32x4){0.f, 0.f, 0.f, 0.f};

    for (int k0 = 0; k0 < DFF; k0 += 32) {
        __syncthreads();
        GLOAD16(a0 + k0, As + ld0);
        GLOAD16(a1 + k0, As + ld1);
        GLOAD16(b0 + k0, Bs + ld0);
        GLOAD16(b1 + k0, Bs + ld1);
        asm volatile("s_waitcnt vmcnt(0)" ::: "memory");
        __syncthreads();

        bf16x8 a[4];
        #pragma unroll
        for (int mi = 0; mi < 4; ++mi)
            a[mi] = *(const bf16x8*)&As[a_base + mi * 512];
        #pragma unroll
        for (int ni = 0; ni < 4; ++ni) {
            const bf16x8 b = *(const bf16x8*)&Bs[b_base + ni * 512];
            #pragma unroll
            for (int mi = 0; mi < 4; ++mi)
                acc[mi][ni] = __builtin_amdgcn_mfma_f32_16x16x32_bf16(a[mi], b, acc[mi][ni], 0, 0, 0);
        }
    }

    #pragma unroll
    for (int mi = 0; mi < 4; ++mi)
        #pragma unroll
        for (int ni = 0; ni < 4; ++ni)
            #pragma unroll
            for (int r = 0; r < 4; ++r) {
                const int row = wr * 64 + mi * 16 + rbase + r;
                const int col = wc * 64 + ni * 16 + lr;
                yb[(size_t)(e * C_CAP + mt * 128 + row) * DM + nt * 128 + col] = acc[mi][ni][r];
            }
}

// ---------------- kernel 5: weighted gather-combine ----------------
__global__ __launch_bounds__(256) void k_combine(
    const float* __restrict__ yb, const int* __restrict__ slot_row,
    const float* __restrict__ slot_w, float* __restrict__ out)
{
    const int t = blockIdx.x, tid = threadIdx.x;
    const int r0 = slot_row[2*t], r1 = slot_row[2*t+1];
    const float p0 = slot_w[2*t], p1 = slot_w[2*t+1];
    float4 acc = make_float4(0.f, 0.f, 0.f, 0.f);
    if (r0 >= 0) {
        const float4 y = *(const float4*)(yb + (size_t)r0 * DM + tid * 4);
        acc.x += p0 * y.x; acc.y += p0 * y.y; acc.z += p0 * y.z; acc.w += p0 * y.w;
    }
    if (r1 >= 0) {
        const float4 y = *(const float4*)(yb + (size_t)r1 * DM + tid * 4);
        acc.x += p1 * y.x; acc.y += p1 * y.y; acc.z += p1 * y.z; acc.w += p1 * y.w;
    }
    *(float4*)(out + (size_t)t * DM + tid * 4) = acc;
}

extern "C" void kernel_launch(void* const* d_in, const int* in_sizes, int n_in,
                              void* d_out, int out_size, void* d_ws, size_t ws_size,
                              hipStream_t stream)
{
    const float* x     = (const float*)d_in[0];
    const float* gamma = (const float*)d_in[1];
    const float* beta  = (const float*)d_in[2];
    const float* rw    = (const float*)d_in[3];
    const float* w12   = (const float*)d_in[4];
    const float* w3    = (const float*)d_in[5];
    float* out = (float*)d_out;

    char* ws = (char*)d_ws;
    __bf16* xnb     = (__bf16*)(ws + 0ull);
    __bf16* w12b    = (__bf16*)(ws + 8388608ull);
    __bf16* w3b     = (__bf16*)(ws + 142606336ull);
    __bf16* h       = (__bf16*)(ws + 209715200ull);
    float*  yb      = (float*) (ws + 293601280ull);
    int*    slot_e  = (int*)   (ws + 335544320ull);
    float*  slot_w  = (float*) (ws + 335577088ull);
    int*    slot_row= (int*)   (ws + 335609856ull);
    int*    row_tok = (int*)   (ws + 335642624ull);
    int*    counts  = (int*)   (ws + 335683584ull);

    hipLaunchKernelGGL(k_cvt, dim3(2048), dim3(256), 0, stream, w12, w12b, 16777216);
    hipLaunchKernelGGL(k_cvt, dim3(2048), dim3(256), 0, stream, w3,  w3b,  8388608);
    hipLaunchKernelGGL(k_ln_router, dim3(T_TOK), dim3(256), 0, stream,
                       x, gamma, beta, rw, xnb, slot_e, slot_w);
    hipLaunchKernelGGL(k_dispatch, dim3(1), dim3(256), 0, stream,
                       slot_e, slot_row, row_tok, counts);
    hipLaunchKernelGGL(k_gemm1, dim3(10, 32, 8), dim3(256), 0, stream,
                       xnb, w12b, row_tok, counts, h);
    hipLaunchKernelGGL(k_gemm2, dim3(10, 8, 8), dim3(256), 0, stream,
                       h, w3b, counts, yb);
    hipLaunchKernelGGL(k_combine, dim3(T_TOK), dim3(256), 0, stream,
                       yb, slot_row, slot_w, out);
}

// Round 3
// 899.756 us; speedup vs baseline: 1.0684x; 1.0684x over previous
//
#include <hip/hip_runtime.h>
#include <hip/hip_bf16.h>

// MoE FFN (dMoE), MI355X. Round 3: fused g/u single-pass GEMM1 + XCD-pinned
// B-panels (panel (e,nt) lives on exactly one XCD's L2).
// Shapes: T=4096, D=1024, F=4096, E=8, K=2, C=1280.
//
// ws layout (bytes), total ~320.2 MiB (unchanged from round 2):
//   xnb   bf16 [T,D]        @ 0
//   w12b  bf16 [E,2F,D]     @ 8388608
//   w3b   bf16 [E,D,F]      @ 142606336
//   h     bf16 [E*C,F]      @ 209715200
//   yb    f32  [E*C,D]      @ 293601280
//   slot_e   int [T*K]      @ 335544320
//   slot_w   f32 [T*K]      @ 335577088
//   slot_row int [T*K]      @ 335609856
//   row_tok  int [E*C]      @ 335642624
//   counts   int [E]        @ 335683584

#define T_TOK   4096
#define DM      1024
#define DFF     4096
#define NE      8
#define C_CAP   1280
#define CLAMP_V 1.0e4f
#define LN_EPS  1e-5f

typedef __attribute__((ext_vector_type(8))) __bf16 bf16x8;
typedef __attribute__((ext_vector_type(4))) __bf16 bf16x4;
typedef __attribute__((ext_vector_type(4))) float  f32x4;

#define GLOAD16(gsrc, ldst)                                                      \
    __builtin_amdgcn_global_load_lds(                                            \
        (const __attribute__((address_space(1))) void*)(gsrc),                   \
        (__attribute__((address_space(3))) void*)(ldst), 16, 0, 0)

// ---------------- kernel 0: fp32 -> bf16 weight conversion ----------------
__global__ __launch_bounds__(256) void k_cvt(const float* __restrict__ s,
                                             __bf16* __restrict__ d, int n4)
{
    int i = blockIdx.x * 256 + threadIdx.x;
    const int stride = gridDim.x * 256;
    for (; i < n4; i += stride) {
        const float4 v = ((const float4*)s)[i];
        bf16x4 o;
        o.x = (__bf16)v.x; o.y = (__bf16)v.y; o.z = (__bf16)v.z; o.w = (__bf16)v.w;
        ((bf16x4*)d)[i] = o;
    }
}

// ---------------- kernel 1: LayerNorm + router logits + top-2 ----------------
__global__ __launch_bounds__(256) void k_ln_router(
    const float* __restrict__ x, const float* __restrict__ gamma,
    const float* __restrict__ beta, const float* __restrict__ rw,
    __bf16* __restrict__ xnb, int* __restrict__ slot_e, float* __restrict__ slot_w)
{
    const int t   = blockIdx.x;
    const int tid = threadIdx.x;
    __shared__ float lds4[4];
    __shared__ float red[4][8];
    __shared__ float logits[8];

    const float4 xv = *(const float4*)(x + (size_t)t * DM + tid * 4);

    float s = xv.x + xv.y + xv.z + xv.w;
    #pragma unroll
    for (int o = 32; o > 0; o >>= 1) s += __shfl_down(s, o, 64);
    if ((tid & 63) == 0) lds4[tid >> 6] = s;
    __syncthreads();
    const float mu = (lds4[0] + lds4[1] + lds4[2] + lds4[3]) * (1.0f / DM);

    float4 d4;
    d4.x = xv.x - mu; d4.y = xv.y - mu; d4.z = xv.z - mu; d4.w = xv.w - mu;
    float v = d4.x*d4.x + d4.y*d4.y + d4.z*d4.z + d4.w*d4.w;
    #pragma unroll
    for (int o = 32; o > 0; o >>= 1) v += __shfl_down(v, o, 64);
    __syncthreads();
    if ((tid & 63) == 0) lds4[tid >> 6] = v;
    __syncthreads();
    const float rstd = rsqrtf((lds4[0]+lds4[1]+lds4[2]+lds4[3]) * (1.0f/DM) + LN_EPS);

    const float4 g4 = *(const float4*)(gamma + tid * 4);
    const float4 b4 = *(const float4*)(beta + tid * 4);
    float4 xnv;
    xnv.x = d4.x * rstd * g4.x + b4.x;
    xnv.y = d4.y * rstd * g4.y + b4.y;
    xnv.z = d4.z * rstd * g4.z + b4.z;
    xnv.w = d4.w * rstd * g4.w + b4.w;
    bf16x4 xb;
    xb.x = (__bf16)xnv.x; xb.y = (__bf16)xnv.y; xb.z = (__bf16)xnv.z; xb.w = (__bf16)xnv.w;
    *(bf16x4*)(xnb + (size_t)t * DM + tid * 4) = xb;

    float part[8];
    #pragma unroll
    for (int e = 0; e < 8; ++e) {
        const float4 w4 = *(const float4*)(rw + (size_t)e * DM + tid * 4);
        part[e] = xnv.x*w4.x + xnv.y*w4.y + xnv.z*w4.z + xnv.w*w4.w;
    }
    #pragma unroll
    for (int e = 0; e < 8; ++e) {
        float p = part[e];
        #pragma unroll
        for (int o = 32; o > 0; o >>= 1) p += __shfl_down(p, o, 64);
        if ((tid & 63) == 0) red[tid >> 6][e] = p;
    }
    __syncthreads();
    if (tid < 8) {
        float l = red[0][tid] + red[1][tid] + red[2][tid] + red[3][tid];
        l = fminf(fmaxf(l, -CLAMP_V), CLAMP_V);
        logits[tid] = l;
    }
    __syncthreads();
    if (tid == 0) {
        int i0 = 0; float v0 = logits[0];
        #pragma unroll
        for (int e = 1; e < 8; ++e) { if (logits[e] > v0) { v0 = logits[e]; i0 = e; } }
        int i1 = (i0 == 0) ? 1 : 0; float v1 = logits[i1];
        #pragma unroll
        for (int e = 0; e < 8; ++e) {
            if (e == i0 || e == ((i0 == 0) ? 1 : 0)) continue;
            if (logits[e] > v1) { v1 = logits[e]; i1 = e; }
        }
        const float ex = __expf(v1 - v0);
        const float denom = 1.0f + ex + 1e-12f;
        slot_e[2*t]   = i0;
        slot_e[2*t+1] = i1;
        slot_w[2*t]   = 1.0f / denom;
        slot_w[2*t+1] = ex / denom;
    }
}

// ---------------- kernel 2: stable dispatch scan (single block) ----------------
__global__ __launch_bounds__(256) void k_dispatch(
    const int* __restrict__ slot_e, int* __restrict__ slot_row,
    int* __restrict__ row_tok, int* __restrict__ counts)
{
    __shared__ int cnt[256][NE];
    const int tid = threadIdx.x;

    for (int i = tid; i < NE * C_CAP; i += 256) row_tok[i] = -1;

    int loc[NE];
    #pragma unroll
    for (int e = 0; e < NE; ++e) loc[e] = 0;
    const int s0 = tid * 32;
    for (int s = s0; s < s0 + 32; ++s) {
        const int e = slot_e[s];
        #pragma unroll
        for (int ee = 0; ee < NE; ++ee) loc[ee] += (e == ee);
    }
    #pragma unroll
    for (int e = 0; e < NE; ++e) cnt[tid][e] = loc[e];
    __syncthreads();

    if (tid < NE) {
        int run = 0;
        for (int t2 = 0; t2 < 256; ++t2) { const int v2 = cnt[t2][tid]; cnt[t2][tid] = run; run += v2; }
        counts[tid] = run < C_CAP ? run : C_CAP;
    }
    __syncthreads();

    #pragma unroll
    for (int e = 0; e < NE; ++e) loc[e] = cnt[tid][e];
    for (int s = s0; s < s0 + 32; ++s) {
        const int e = slot_e[s];
        int pos = 0;
        #pragma unroll
        for (int ee = 0; ee < NE; ++ee) if (e == ee) { pos = loc[ee]; loc[ee] = pos + 1; }
        if (pos < C_CAP) {
            const int row = e * C_CAP + pos;
            slot_row[s] = row;
            row_tok[row] = s >> 1;
        } else {
            slot_row[s] = -1;
        }
    }
}

// ---------------- kernel 3: GEMM1, fused g+u single K-pass + SwiGLU ----------
// Block: 128 rows x 64 f-cols, computes g AND u for the same f (silu in-reg).
// 4 waves (2 row-halves x 2 col-halves); per wave: 4x2 frags of g + 4x2 of u.
// XCD mapping: B-panel (e,nt) pinned to xcd = nt&7; A-tile (e,mt) L2-reused
// across the 8 consecutive same-XCD nt-blocks.
__global__ __launch_bounds__(256) void k_gemm1(
    const __bf16* __restrict__ xnb, const __bf16* __restrict__ w12b,
    const int* __restrict__ row_tok, const int* __restrict__ counts,
    __bf16* __restrict__ h)
{
    const int b     = blockIdx.x;          // 0..5119
    const int e     = b / 640;
    const int local = b % 640;
    const int xcd   = local & 7;
    const int j     = local >> 3;          // 0..79
    const int mt    = j >> 3;              // 0..9
    const int nt    = ((j & 7) << 3) | xcd;// 0..63 ; nt&7 == xcd
    if (mt * 128 >= counts[e]) return;

    __shared__ __align__(16) __bf16 As[128 * 32];   // 8 KB: m-rows
    __shared__ __align__(16) __bf16 Bs[128 * 32];   // 8 KB: rows 0..63 = g cols, 64..127 = u cols

    const int tid  = threadIdx.x;
    const int wid  = tid >> 6, lane = tid & 63;
    const int wr   = wid >> 1, wc = wid & 1;

    // staging maps: thread stages element idx (tid) and (256+tid); row = idx>>2, 16B chunk = idx&3
    const int r0  = tid >> 2;              // 0..63
    const int kc0 = (tid & 3) * 8;         // bf16 k-offset within 32
    int t0 = row_tok[e * C_CAP + mt * 128 + r0];      if (t0 < 0) t0 = 0;
    int t1 = row_tok[e * C_CAP + mt * 128 + 64 + r0]; if (t1 < 0) t1 = 0;
    const __bf16* a0 = xnb + (size_t)t0 * DM + kc0;
    const __bf16* a1 = xnb + (size_t)t1 * DM + kc0;
    const __bf16* b0 = w12b + ((size_t)e * (2*DFF) + nt * 64 + r0) * DM + kc0;        // g
    const __bf16* b1 = w12b + ((size_t)e * (2*DFF) + DFF + nt * 64 + r0) * DM + kc0;  // u
    const int ld0 = wid * 512;             // bf16 elems (wave-uniform LDS base)
    const int ld1 = 2048 + wid * 512;

    const int lr = lane & 15, lk = (lane >> 4) * 8;
    const int a_base  = (wr * 64 + lr) * 32 + lk;
    const int bg_base = (wc * 32 + lr) * 32 + lk;
    const int bu_base = (64 + wc * 32 + lr) * 32 + lk;
    const int rbase   = (lane >> 4) * 4;

    f32x4 accg[4][2], accu[4][2];
    #pragma unroll
    for (int mi = 0; mi < 4; ++mi)
        #pragma unroll
        for (int ni = 0; ni < 2; ++ni) {
            accg[mi][ni] = (f32x4){0.f, 0.f, 0.f, 0.f};
            accu[mi][ni] = (f32x4){0.f, 0.f, 0.f, 0.f};
        }

    for (int k0 = 0; k0 < DM; k0 += 32) {
        __syncthreads();
        GLOAD16(a0 + k0, As + ld0);
        GLOAD16(a1 + k0, As + ld1);
        GLOAD16(b0 + k0, Bs + ld0);
        GLOAD16(b1 + k0, Bs + ld1);
        asm volatile("s_waitcnt vmcnt(0)" ::: "memory");
        __syncthreads();

        bf16x8 a[4];
        #pragma unroll
        for (int mi = 0; mi < 4; ++mi)
            a[mi] = *(const bf16x8*)&As[a_base + mi * 512];
        #pragma unroll
        for (int ni = 0; ni < 2; ++ni) {
            const bf16x8 bg = *(const bf16x8*)&Bs[bg_base + ni * 512];
            const bf16x8 bu = *(const bf16x8*)&Bs[bu_base + ni * 512];
            #pragma unroll
            for (int mi = 0; mi < 4; ++mi) {
                accg[mi][ni] = __builtin_amdgcn_mfma_f32_16x16x32_bf16(a[mi], bg, accg[mi][ni], 0, 0, 0);
                accu[mi][ni] = __builtin_amdgcn_mfma_f32_16x16x32_bf16(a[mi], bu, accu[mi][ni], 0, 0, 0);
            }
        }
    }

    // epilogue: h = silu(g) * u  (g stays fp32 — no bf16 round-trip)
    #pragma unroll
    for (int mi = 0; mi < 4; ++mi)
        #pragma unroll
        for (int ni = 0; ni < 2; ++ni)
            #pragma unroll
            for (int r = 0; r < 4; ++r) {
                const int row = mt * 128 + wr * 64 + mi * 16 + rbase + r;
                const int col = nt * 64 + wc * 32 + ni * 16 + lr;
                const float g = accg[mi][ni][r];
                const float u = accu[mi][ni][r];
                const float o = (g / (1.0f + __expf(-g))) * u;
                h[(size_t)(e * C_CAP + row) * DFF + col] = (__bf16)o;
            }
}

// ---------------- kernel 4: GEMM2 bf16 MFMA, fp32 out ----------------
// XCD mapping: w3 panel (e,nt) pinned to xcd = nt (8 panels, 8 XCDs);
// panel (1 MB) stays L2-resident across all 10 mt.
__global__ __launch_bounds__(256) void k_gemm2(
    const __bf16* __restrict__ h, const __bf16* __restrict__ w3b,
    const int* __restrict__ counts, float* __restrict__ yb)
{
    const int b     = blockIdx.x;          // 0..639
    const int e     = b / 80;
    const int local = b % 80;
    const int nt    = local & 7;           // == xcd
    const int mt    = local >> 3;          // 0..9
    if (mt * 128 >= counts[e]) return;

    __shared__ __align__(16) __bf16 As[128 * 32];
    __shared__ __align__(16) __bf16 Bs[128 * 32];

    const int tid  = threadIdx.x;
    const int wid  = tid >> 6, lane = tid & 63;
    const int wr   = wid >> 1, wc = wid & 1;

    const int r0  = tid >> 2;
    const int kc0 = (tid & 3) * 8;
    const __bf16* a0 = h + (size_t)(e * C_CAP + mt * 128 + r0) * DFF + kc0;
    const __bf16* a1 = h + (size_t)(e * C_CAP + mt * 128 + 64 + r0) * DFF + kc0;
    const __bf16* b0 = w3b + ((size_t)e * DM + nt * 128 + r0) * DFF + kc0;
    const __bf16* b1 = w3b + ((size_t)e * DM + nt * 128 + 64 + r0) * DFF + kc0;
    const int ld0 = wid * 512;
    const int ld1 = 2048 + wid * 512;

    const int lr = lane & 15, lk = (lane >> 4) * 8;
    const int a_base = (wr * 64 + lr) * 32 + lk;
    const int b_base = (wc * 64 + lr) * 32 + lk;
    const int rbase  = (lane >> 4) * 4;

    f32x4 acc[4][4];
    #pragma unroll
    for (int mi = 0; mi < 4; ++mi)
        #pragma unroll
        for (int ni = 0; ni < 4; ++ni) acc[mi][ni] = (f32x4){0.f, 0.f, 0.f, 0.f};

    for (int k0 = 0; k0 < DFF; k0 += 32) {
        __syncthreads();
        GLOAD16(a0 + k0, As + ld0);
        GLOAD16(a1 + k0, As + ld1);
        GLOAD16(b0 + k0, Bs + ld0);
        GLOAD16(b1 + k0, Bs + ld1);
        asm volatile("s_waitcnt vmcnt(0)" ::: "memory");
        __syncthreads();

        bf16x8 a[4];
        #pragma unroll
        for (int mi = 0; mi < 4; ++mi)
            a[mi] = *(const bf16x8*)&As[a_base + mi * 512];
        #pragma unroll
        for (int ni = 0; ni < 4; ++ni) {
            const bf16x8 bv = *(const bf16x8*)&Bs[b_base + ni * 512];
            #pragma unroll
            for (int mi = 0; mi < 4; ++mi)
                acc[mi][ni] = __builtin_amdgcn_mfma_f32_16x16x32_bf16(a[mi], bv, acc[mi][ni], 0, 0, 0);
        }
    }

    #pragma unroll
    for (int mi = 0; mi < 4; ++mi)
        #pragma unroll
        for (int ni = 0; ni < 4; ++ni)
            #pragma unroll
            for (int r = 0; r < 4; ++r) {
                const int row = wr * 64 + mi * 16 + rbase + r;
                const int col = wc * 64 + ni * 16 + lr;
                yb[(size_t)(e * C_CAP + mt * 128 + row) * DM + nt * 128 + col] = acc[mi][ni][r];
            }
}

// ---------------- kernel 5: weighted gather-combine ----------------
__global__ __launch_bounds__(256) void k_combine(
    const float* __restrict__ yb, const int* __restrict__ slot_row,
    const float* __restrict__ slot_w, float* __restrict__ out)
{
    const int t = blockIdx.x, tid = threadIdx.x;
    const int r0 = slot_row[2*t], r1 = slot_row[2*t+1];
    const float p0 = slot_w[2*t], p1 = slot_w[2*t+1];
    float4 acc = make_float4(0.f, 0.f, 0.f, 0.f);
    if (r0 >= 0) {
        const float4 y = *(const float4*)(yb + (size_t)r0 * DM + tid * 4);
        acc.x += p0 * y.x; acc.y += p0 * y.y; acc.z += p0 * y.z; acc.w += p0 * y.w;
    }
    if (r1 >= 0) {
        const float4 y = *(const float4*)(yb + (size_t)r1 * DM + tid * 4);
        acc.x += p1 * y.x; acc.y += p1 * y.y; acc.z += p1 * y.z; acc.w += p1 * y.w;
    }
    *(float4*)(out + (size_t)t * DM + tid * 4) = acc;
}

extern "C" void kernel_launch(void* const* d_in, const int* in_sizes, int n_in,
                              void* d_out, int out_size, void* d_ws, size_t ws_size,
                              hipStream_t stream)
{
    const float* x     = (const float*)d_in[0];
    const float* gamma = (const float*)d_in[1];
    const float* beta  = (const float*)d_in[2];
    const float* rw    = (const float*)d_in[3];
    const float* w12   = (const float*)d_in[4];
    const float* w3    = (const float*)d_in[5];
    float* out = (float*)d_out;

    char* ws = (char*)d_ws;
    __bf16* xnb     = (__bf16*)(ws + 0ull);
    __bf16* w12b    = (__bf16*)(ws + 8388608ull);
    __bf16* w3b     = (__bf16*)(ws + 142606336ull);
    __bf16* h       = (__bf16*)(ws + 209715200ull);
    float*  yb      = (float*) (ws + 293601280ull);
    int*    slot_e  = (int*)   (ws + 335544320ull);
    float*  slot_w  = (float*) (ws + 335577088ull);
    int*    slot_row= (int*)   (ws + 335609856ull);
    int*    row_tok = (int*)   (ws + 335642624ull);
    int*    counts  = (int*)   (ws + 335683584ull);

    hipLaunchKernelGGL(k_cvt, dim3(4096), dim3(256), 0, stream, w12, w12b, 16777216);
    hipLaunchKernelGGL(k_cvt, dim3(4096), dim3(256), 0, stream, w3,  w3b,  8388608);
    hipLaunchKernelGGL(k_ln_router, dim3(T_TOK), dim3(256), 0, stream,
                       x, gamma, beta, rw, xnb, slot_e, slot_w);
    hipLaunchKernelGGL(k_dispatch, dim3(1), dim3(256), 0, stream,
                       slot_e, slot_row, row_tok, counts);
    hipLaunchKernelGGL(k_gemm1, dim3(5120), dim3(256), 0, stream,
                       xnb, w12b, row_tok, counts, h);
    hipLaunchKernelGGL(k_gemm2, dim3(640), dim3(256), 0, stream,
                       h, w3b, counts, yb);
    hipLaunchKernelGGL(k_combine, dim3(T_TOK), dim3(256), 0, stream,
                       yb, slot_row, slot_w, out);
}